// Round 1
// baseline (278.049 us; speedup 1.0000x reference)
//
#include <hip/hip_runtime.h>
#include <math.h>

// Problem constants (B=4, H=16, S=4096, D=64)
#define BH 64
#define SEQ 4096
#define DIM 64
#define CHUNK 64
#define NCHUNK (SEQ / CHUNK)   // 64

__device__ __forceinline__ float fast_rcp(float x)  { return __builtin_amdgcn_rcpf(x); }
__device__ __forceinline__ float fast_rsqrt(float x){ return __builtin_amdgcn_rsqf(x); }

__device__ __forceinline__ float fast_sigmoid(float x) {
    // 1 / (1 + e^-x); v_exp_f32 + v_rcp_f32
    return fast_rcp(1.0f + __expf(-x));
}

// ---------------------------------------------------------------------------
// Pass 1: per-chunk sums of v_swiglu = v*v*sigmoid(v), one wave per chunk,
// lane = d. Output P[blk*64 + d], blk = bh*NCHUNK + ck.
// ---------------------------------------------------------------------------
__global__ __launch_bounds__(64) void k_chunksum(const float* __restrict__ V,
                                                 float* __restrict__ P) {
    const int blk  = blockIdx.x;            // bh*NCHUNK + ck
    const int lane = threadIdx.x;           // d
    // (bh*NCHUNK + ck) * CHUNK * DIM == bh*SEQ*DIM + ck*CHUNK*DIM  (NCHUNK*CHUNK == SEQ)
    const float* vp = V + (size_t)blk * (CHUNK * DIM) + lane;
    float acc = 0.0f;
#pragma unroll 8
    for (int j = 0; j < CHUNK; ++j) {
        float v = vp[j * DIM];
        acc += v * v * fast_sigmoid(v);
    }
    P[(size_t)blk * DIM + lane] = acc;
}

// ---------------------------------------------------------------------------
// Pass 1.5: in-place exclusive prefix over chunks, per (b,h), lane = d.
// ---------------------------------------------------------------------------
__global__ __launch_bounds__(64) void k_prefix(float* __restrict__ P) {
    const int bh   = blockIdx.x;
    const int lane = threadIdx.x;
    float* p = P + (size_t)bh * (NCHUNK * DIM) + lane;
    float run = 0.0f;
#pragma unroll 4
    for (int ck = 0; ck < NCHUNK; ++ck) {
        float t = p[ck * DIM];
        p[ck * DIM] = run;
        run += t;
    }
}

// ---------------------------------------------------------------------------
// Pass 2: sequential scan within each chunk. One wave per chunk, lane = d.
// Per row: c += v*v*sig(v); rms(c); r = |Q|+|K|+1; m = rms_c(c)/r;
// o = v*(1+silu(m)); out = rms(o).
// Reductions over D=64 lanes via 6-step butterfly; q2/k2/c2 packed together.
// ---------------------------------------------------------------------------
__global__ __launch_bounds__(64) void k_scan(const float* __restrict__ Q,
                                             const float* __restrict__ K,
                                             const float* __restrict__ V,
                                             const float* __restrict__ P,
                                             float* __restrict__ O) {
    const int blk  = blockIdx.x;            // bh*NCHUNK + ck
    const int lane = threadIdx.x;           // d
    const size_t base = (size_t)blk * (CHUNK * DIM) + lane;
    const float* qp = Q + base;
    const float* kp = K + base;
    const float* vp = V + base;
    float*       op = O + base;

    float c = P[(size_t)blk * DIM + lane];  // exclusive prefix for this chunk

    // software prefetch row 0
    float v = vp[0];
    float q = qp[0];
    float k = kp[0];

    for (int j = 0; j < CHUNK; ++j) {
        // issue next row's loads before this row's shuffle chains
        const int jn = (j + 1 < CHUNK) ? (j + 1) : (CHUNK - 1);
        float vn = vp[jn * DIM];
        float qn = qp[jn * DIM];
        float kn = kp[jn * DIM];

        float sw = v * v * fast_sigmoid(v);
        c += sw;

        float c2 = c * c;
        float q2 = q * q;
        float k2 = k * k;
#pragma unroll
        for (int m = 1; m < 64; m <<= 1) {
            c2 += __shfl_xor(c2, m);
            q2 += __shfl_xor(q2, m);
            k2 += __shfl_xor(k2, m);
        }

        float rms_c = fast_rsqrt(c2 * (1.0f / 64.0f) + 1e-5f);
        float r     = sqrtf(q2) + sqrtf(k2) + 1.0f;     // (+2e-8 is below fp32 ulp here)
        float scale = rms_c * fast_rcp(r);

        float m_  = c * scale;
        float sil = m_ * fast_sigmoid(m_);
        float o   = v * (1.0f + sil);

        float o2 = o * o;
#pragma unroll
        for (int m = 1; m < 64; m <<= 1) {
            o2 += __shfl_xor(o2, m);
        }
        float outv = o * fast_rsqrt(o2 * (1.0f / 64.0f) + 1e-5f);
        op[j * DIM] = outv;

        v = vn; q = qn; k = kn;
    }
}

// ---------------------------------------------------------------------------
extern "C" void kernel_launch(void* const* d_in, const int* in_sizes, int n_in,
                              void* d_out, int out_size, void* d_ws, size_t ws_size,
                              hipStream_t stream) {
    const float* Q = (const float*)d_in[0];
    const float* K = (const float*)d_in[1];
    const float* V = (const float*)d_in[2];
    float* O = (float*)d_out;
    float* P = (float*)d_ws;    // BH*NCHUNK*DIM floats = 1 MB

    k_chunksum<<<BH * NCHUNK, 64, 0, stream>>>(V, P);
    k_prefix<<<BH, 64, 0, stream>>>(P);
    k_scan<<<BH * NCHUNK, 64, 0, stream>>>(Q, K, V, P, O);
}

// Round 2
// 253.272 us; speedup vs baseline: 1.0978x; 1.0978x over previous
//
#include <hip/hip_runtime.h>
#include <math.h>

// Problem constants (B=4, H=16, S=4096, D=64)
#define BH 64
#define SEQ 4096
#define DIM 64
#define CHUNK 32
#define NCHUNK (SEQ / CHUNK)   // 128
#define WPB 4                  // waves per block (256-thread blocks)

__device__ __forceinline__ float fast_rcp(float x)  { return __builtin_amdgcn_rcpf(x); }
__device__ __forceinline__ float fast_rsqrt(float x){ return __builtin_amdgcn_rsqf(x); }

__device__ __forceinline__ float fast_sigmoid(float x) {
    return fast_rcp(1.0f + __expf(-x));
}

// ---------------------------------------------------------------------------
// Pass 1: per chunk (32 rows), one wave, lane = d.
//   - chunk partial sums of v_swiglu = v*v*sigmoid(v)     -> P[chunk*64 + d]
//   - per-row gate r = ||Q|| + ||K|| + 1                  -> R[row]
// Reads Q,K,V (192 MB) — BW-bound pass.
// ---------------------------------------------------------------------------
__global__ __launch_bounds__(256) void k_partials(const float* __restrict__ Q,
                                                  const float* __restrict__ K,
                                                  const float* __restrict__ V,
                                                  float* __restrict__ P,
                                                  float* __restrict__ R) {
    const int wave  = threadIdx.x >> 6;
    const int lane  = threadIdx.x & 63;
    const int chunk = blockIdx.x * WPB + wave;     // bh*NCHUNK + ck
    const size_t base = (size_t)chunk * (CHUNK * DIM) + lane;
    const float* qp = Q + base;
    const float* kp = K + base;
    const float* vp = V + base;

    float acc  = 0.0f;
    float my_r = 0.0f;   // lane j keeps row j's r
#pragma unroll 8
    for (int j = 0; j < CHUNK; ++j) {
        float q = qp[j * DIM];
        float k = kp[j * DIM];
        float v = vp[j * DIM];
        acc += v * v * fast_sigmoid(v);

        float q2 = q * q;
        float k2 = k * k;
#pragma unroll
        for (int m = 1; m < 64; m <<= 1) {
            q2 += __shfl_xor(q2, m);
            k2 += __shfl_xor(k2, m);
        }
        float r = sqrtf(q2) + sqrtf(k2) + 1.0f;
        if (lane == j) my_r = r;
    }
    P[(size_t)chunk * DIM + lane] = acc;
    if (lane < CHUNK) R[(size_t)chunk * CHUNK + lane] = my_r;  // coalesced 128 B
}

// ---------------------------------------------------------------------------
// Pass 1.5: in-place exclusive prefix over chunks, per (b,h), lane = d.
// ---------------------------------------------------------------------------
__global__ __launch_bounds__(64) void k_prefix(float* __restrict__ P) {
    const int bh   = blockIdx.x;
    const int lane = threadIdx.x;
    float* p = P + (size_t)bh * (NCHUNK * DIM) + lane;
    float run = 0.0f;
#pragma unroll 8
    for (int ck = 0; ck < NCHUNK; ++ck) {
        float t = p[ck * DIM];
        p[ck * DIM] = run;
        run += t;
    }
}

// ---------------------------------------------------------------------------
// Pass 2: sequential scan within each chunk. One wave per chunk, lane = d,
// 4 waves per block for full occupancy. Reads V (L3-warm), P, R; writes O.
// Per row: c += v*v*sig(v); rms(c); m = rms_c(c)/r; o = v*(1+silu(m));
// out = rms(o). Two 6-step butterflies per row.
// ---------------------------------------------------------------------------
__global__ __launch_bounds__(256) void k_scan(const float* __restrict__ V,
                                              const float* __restrict__ P,
                                              const float* __restrict__ R,
                                              float* __restrict__ O) {
    const int wave  = threadIdx.x >> 6;
    const int lane  = threadIdx.x & 63;
    const int chunk = blockIdx.x * WPB + wave;     // bh*NCHUNK + ck
    const size_t base = (size_t)chunk * (CHUNK * DIM) + lane;
    const float* vp = V + base;
    float*       op = O + base;
    const float* rp = R + (size_t)chunk * CHUNK;

    float c = P[(size_t)chunk * DIM + lane];       // exclusive prefix

#pragma unroll 8
    for (int j = 0; j < CHUNK; ++j) {
        float v = vp[j * DIM];
        float r = rp[j];                            // lane-uniform scalar

        float sw = v * v * fast_sigmoid(v);
        c += sw;

        float c2 = c * c;
#pragma unroll
        for (int m = 1; m < 64; m <<= 1) c2 += __shfl_xor(c2, m);

        float rms_c = fast_rsqrt(c2 * (1.0f / 64.0f) + 1e-5f);
        float m_    = c * rms_c * fast_rcp(r);
        float o     = v * (1.0f + m_ * fast_sigmoid(m_));

        float o2 = o * o;
#pragma unroll
        for (int m = 1; m < 64; m <<= 1) o2 += __shfl_xor(o2, m);

        op[j * DIM] = o * fast_rsqrt(o2 * (1.0f / 64.0f) + 1e-5f);
    }
}

// ---------------------------------------------------------------------------
extern "C" void kernel_launch(void* const* d_in, const int* in_sizes, int n_in,
                              void* d_out, int out_size, void* d_ws, size_t ws_size,
                              hipStream_t stream) {
    const float* Q = (const float*)d_in[0];
    const float* K = (const float*)d_in[1];
    const float* V = (const float*)d_in[2];
    float* O = (float*)d_out;
    float* P = (float*)d_ws;                          // 64*128*64 floats = 2 MB
    float* R = (float*)d_ws + (size_t)BH * NCHUNK * DIM; // 64*4096 floats = 1 MB

    const int nchunks = BH * NCHUNK;                  // 8192
    k_partials<<<nchunks / WPB, 256, 0, stream>>>(Q, K, V, P, R);
    k_prefix<<<BH, 64, 0, stream>>>(P);
    k_scan<<<nchunks / WPB, 256, 0, stream>>>(V, P, R, O);
}

// Round 3
// 230.546 us; speedup vs baseline: 1.2060x; 1.0986x over previous
//
#include <hip/hip_runtime.h>
#include <math.h>

// Problem constants (B=4, H=16, S=4096, D=64)
#define BH 64
#define SEQ 4096
#define DIM 64
#define CHUNK 32
#define NCHUNK (SEQ / CHUNK)   // 128
#define WPB 4                  // waves per block (256-thread blocks)

__device__ __forceinline__ float fast_rcp(float x)  { return __builtin_amdgcn_rcpf(x); }
__device__ __forceinline__ float fast_rsqrt(float x){ return __builtin_amdgcn_rsqf(x); }
__device__ __forceinline__ float fast_sigmoid(float x) {
    return fast_rcp(1.0f + __expf(-x));
}

// Lane layout for the big kernels: lane = g*16 + h.
//   g = lane>>4   : row-slot (4 rows in flight per wave)
//   h = lane&15   : d-quad index; lane holds d = h*4 + {0,1,2,3} as float4.
// In-group reductions use xor masks 1,2,4,8 (never cross the 16-lane group).

// ---------------------------------------------------------------------------
// Pass 1: per chunk (32 rows), one wave.
//   - chunk partial sums of v_swiglu = v*v*sigmoid(v)  -> P[chunk*64 + d]
//   - per-row gate r = ||Q|| + ||K|| + 1               -> R[row]
// ---------------------------------------------------------------------------
__global__ __launch_bounds__(256) void k_partials(const float* __restrict__ Q,
                                                  const float* __restrict__ K,
                                                  const float* __restrict__ V,
                                                  float* __restrict__ P,
                                                  float* __restrict__ R) {
    const int wave  = threadIdx.x >> 6;
    const int lane  = threadIdx.x & 63;
    const int g     = lane >> 4;
    const int h     = lane & 15;
    const int chunk = blockIdx.x * WPB + wave;

    const size_t cbase = (size_t)chunk * (CHUNK * DIM);
    const float4* q4 = (const float4*)(Q + cbase);
    const float4* k4 = (const float4*)(K + cbase);
    const float4* v4 = (const float4*)(V + cbase);

    float acc0 = 0.f, acc1 = 0.f, acc2 = 0.f, acc3 = 0.f;

#pragma unroll
    for (int j0 = 0; j0 < CHUNK; j0 += 4) {
        const int row = j0 + g;
        const int idx = row * 16 + h;
        float4 q = q4[idx];
        float4 k = k4[idx];
        float4 v = v4[idx];

        float q2 = q.x*q.x + q.y*q.y + q.z*q.z + q.w*q.w;
        float k2 = k.x*k.x + k.y*k.y + k.z*k.z + k.w*k.w;
#pragma unroll
        for (int m = 1; m < 16; m <<= 1) {
            q2 += __shfl_xor(q2, m);
            k2 += __shfl_xor(k2, m);
        }
        float r = sqrtf(q2) + sqrtf(k2) + 1.0f;
        if (h == 0) R[(size_t)chunk * CHUNK + row] = r;

        acc0 += v.x * v.x * fast_sigmoid(v.x);
        acc1 += v.y * v.y * fast_sigmoid(v.y);
        acc2 += v.z * v.z * fast_sigmoid(v.z);
        acc3 += v.w * v.w * fast_sigmoid(v.w);
    }

    // combine the 4 row-slot groups' partial sums (same h, different g)
#pragma unroll
    for (int m = 16; m < 64; m <<= 1) {
        acc0 += __shfl_xor(acc0, m);
        acc1 += __shfl_xor(acc1, m);
        acc2 += __shfl_xor(acc2, m);
        acc3 += __shfl_xor(acc3, m);
    }
    if (g == 0) {
        float4 out = {acc0, acc1, acc2, acc3};
        ((float4*)(P + (size_t)chunk * DIM))[h] = out;
    }
}

// ---------------------------------------------------------------------------
// Pass 1.5: exclusive prefix over chunks per (b,h), 4 waves/block + LDS carry.
// Wave w scans chunks [w*32, w*32+32) in registers.
// ---------------------------------------------------------------------------
__global__ __launch_bounds__(256) void k_prefix(float* __restrict__ P) {
    __shared__ float seg[WPB][DIM];
    const int wave = threadIdx.x >> 6;
    const int lane = threadIdx.x & 63;
    const int bh   = blockIdx.x;
    const int SEG  = NCHUNK / WPB;   // 32

    float* p = P + (size_t)bh * (NCHUNK * DIM) + (size_t)wave * SEG * DIM + lane;

    float t[SEG];
#pragma unroll
    for (int i = 0; i < SEG; ++i) t[i] = p[i * DIM];

    float run = 0.f;
#pragma unroll
    for (int i = 0; i < SEG; ++i) { float x = t[i]; t[i] = run; run += x; }

    seg[wave][lane] = run;
    __syncthreads();

    float carry = 0.f;
#pragma unroll
    for (int w = 0; w < WPB; ++w)
        if (w < wave) carry += seg[w][lane];

#pragma unroll
    for (int i = 0; i < SEG; ++i) p[i * DIM] = t[i] + carry;
}

// ---------------------------------------------------------------------------
// Pass 2: sequential scan within each chunk, 4 rows in flight.
// c-state (per d) replicated across the 4 row-slot groups as float4/lane.
// Cross-group 2-step inclusive scan combines the 4 rows' sw contributions.
// ---------------------------------------------------------------------------
__global__ __launch_bounds__(256) void k_scan(const float* __restrict__ V,
                                              const float* __restrict__ P,
                                              const float* __restrict__ R,
                                              float* __restrict__ O) {
    const int wave  = threadIdx.x >> 6;
    const int lane  = threadIdx.x & 63;
    const int g     = lane >> 4;
    const int h     = lane & 15;
    const int chunk = blockIdx.x * WPB + wave;

    const size_t cbase = (size_t)chunk * (CHUNK * DIM);
    const float4* v4 = (const float4*)(V + cbase);
    float4*       o4 = (float4*)(O + cbase);
    const float*  rp = R + (size_t)chunk * CHUNK;

    // carry (exclusive prefix for this chunk), replicated across groups
    float4 cb = ((const float4*)(P + (size_t)chunk * DIM))[h];
    float c_base[4] = {cb.x, cb.y, cb.z, cb.w};

    const int up16 = (lane + 48) & 63;   // lane-16 with wrap (masked out for g<1)
    const int up32 = (lane + 32) & 63;   // lane-32 with wrap (masked out for g<2)
    const int src3 = 48 + h;             // group-3 lane with same h

#pragma unroll
    for (int j0 = 0; j0 < CHUNK; j0 += 4) {
        const int row = j0 + g;
        float4 v = v4[row * 16 + h];

        float sw[4];
        sw[0] = v.x * v.x * fast_sigmoid(v.x);
        sw[1] = v.y * v.y * fast_sigmoid(v.y);
        sw[2] = v.z * v.z * fast_sigmoid(v.z);
        sw[3] = v.w * v.w * fast_sigmoid(v.w);

        // inclusive scan over the 4 row-slot groups (element-wise per d)
#pragma unroll
        for (int i = 0; i < 4; ++i) {
            float t = __shfl(sw[i], up16);
            sw[i] += (g >= 1) ? t : 0.f;
        }
#pragma unroll
        for (int i = 0; i < 4; ++i) {
            float t = __shfl(sw[i], up32);
            sw[i] += (g >= 2) ? t : 0.f;
        }

        float c_row[4], tot[4];
#pragma unroll
        for (int i = 0; i < 4; ++i) {
            tot[i]   = __shfl(sw[i], src3);      // full 4-row sum (group 3)
            c_row[i] = c_base[i] + sw[i];        // c at this group's row
            c_base[i] += tot[i];                 // carry for next 4 rows
        }

        float c2 = c_row[0]*c_row[0] + c_row[1]*c_row[1]
                 + c_row[2]*c_row[2] + c_row[3]*c_row[3];
#pragma unroll
        for (int m = 1; m < 16; m <<= 1) c2 += __shfl_xor(c2, m);

        float r     = rp[row];                   // uniform within group
        float rms_c = fast_rsqrt(c2 * (1.0f / 64.0f) + 1e-5f);
        float s     = rms_c * fast_rcp(r);

        float vv[4] = {v.x, v.y, v.z, v.w};
        float o[4];
#pragma unroll
        for (int i = 0; i < 4; ++i) {
            float m_ = c_row[i] * s;
            o[i] = vv[i] * (1.0f + m_ * fast_sigmoid(m_));
        }

        float o2 = o[0]*o[0] + o[1]*o[1] + o[2]*o[2] + o[3]*o[3];
#pragma unroll
        for (int m = 1; m < 16; m <<= 1) o2 += __shfl_xor(o2, m);

        float rms_o = fast_rsqrt(o2 * (1.0f / 64.0f) + 1e-5f);
        float4 out = {o[0]*rms_o, o[1]*rms_o, o[2]*rms_o, o[3]*rms_o};
        o4[row * 16 + h] = out;
    }
}

// ---------------------------------------------------------------------------
extern "C" void kernel_launch(void* const* d_in, const int* in_sizes, int n_in,
                              void* d_out, int out_size, void* d_ws, size_t ws_size,
                              hipStream_t stream) {
    const float* Q = (const float*)d_in[0];
    const float* K = (const float*)d_in[1];
    const float* V = (const float*)d_in[2];
    float* O = (float*)d_out;
    float* P = (float*)d_ws;                              // 8192*64 floats = 2 MB
    float* R = (float*)d_ws + (size_t)BH * NCHUNK * DIM;  // 64*4096 floats = 1 MB

    const int nchunks = BH * NCHUNK;                      // 8192
    k_partials<<<nchunks / WPB, 256, 0, stream>>>(Q, K, V, P, R);
    k_prefix<<<BH, 256, 0, stream>>>(P);
    k_scan<<<nchunks / WPB, 256, 0, stream>>>(V, P, R, O);
}